// Round 10
// baseline (279.369 us; speedup 1.0000x reference)
//
#include <hip/hip_runtime.h>
#include <hip/hip_bf16.h>
#include <math.h>

#define IN_CH 128
#define HID 64
#define OUT_CH 40
#define NBUCK 1024
#define NBSHIFT 10
#define CAP2 3125     // bins2 slots per bucket (2x mean 1563); 1024*3125*8B = 25.6MB
#define CAPL 2560     // LDS records per bucket in k_csr (~25 sigma above mean)

typedef const __hip_bfloat16* bf16p;
typedef __attribute__((ext_vector_type(8))) short bf16x8;
typedef __attribute__((ext_vector_type(4))) float f32x4;
typedef __attribute__((ext_vector_type(8))) float f32x8;

// bf16 -> f32 is exact: shift into the high half
__device__ __forceinline__ f32x8 cvt8(bf16x8 v) {
    f32x8 o;
    #pragma unroll
    for (int j = 0; j < 8; ++j) {
        unsigned int bits = ((unsigned int)(unsigned short)v[j]) << 16;
        o[j] = __uint_as_float(bits);
    }
    return o;
}

__device__ __forceinline__ bf16x8 pack8(f32x8 v) {
    bf16x8 o;
    #pragma unroll
    for (int j = 0; j < 8; ++j) {
        __hip_bfloat16 b = __float2bfloat16(v[j]);
        o[j] = *reinterpret_cast<short*>(&b);
    }
    return o;
}

// exact bucket of column c: b s.t. b*N <= c*1024 < (b+1)*N. Float approx + exact
// 64-bit-mul fixup (no divide; fixup loops run <=1 iteration).
__device__ __forceinline__ int bucket_of(int c, int N, float invNB) {
    int b = (int)((float)c * invNB);
    long long cB = (long long)c << NBSHIFT;
    while ((long long)(b + 1) * N <= cB) ++b;
    while (b > 0 && (long long)b * N > cB) --b;
    return b;
}

// ---- fused flag detection + weight conversion + bincnt2 zeroing (1 block).
__global__ __launch_bounds__(256) void k_detectconv(const void* x, const void* ei,
        int* flags, const void* W1, const void* b1, const void* W2, const void* b2,
        float* wf, int* bincnt2) {
    __shared__ int s_f32, s_hi;
    if (threadIdx.x == 0) { s_f32 = 0; s_hi = 0; }
    __syncthreads();
    const __hip_bfloat16* xb = (const __hip_bfloat16*)x;
    const int* ii = (const int*)ei;
    int lf = 0, lh = 0;
    for (int i = threadIdx.x; i < 4096; i += 256) {
        float f = __bfloat162float(xb[i]);
        if (!(fabsf(f) <= 1e4f)) lf = 1;       // huge/NaN -> buffer is really f32
        lh |= ii[2 * i + 1];                    // int64 high words are all zero
    }
    if (lf) atomicOr(&s_f32, 1);
    if (lh) atomicOr(&s_hi, 1);
    for (int i = threadIdx.x; i < NBUCK; i += 256) bincnt2[i] = 0;
    __syncthreads();
    const int isF32 = s_f32 ? 1 : 0;
    if (threadIdx.x == 0) {
        flags[0] = isF32;
        flags[1] = (s_hi == 0) ? 1 : 0;
        flags[2] = 0;
    }
    for (int i = threadIdx.x; i < 10856; i += 256) {
        const void* src; int off;
        if (i < 8192)       { src = W1; off = i; }
        else if (i < 8256)  { src = b1; off = i - 8192; }
        else if (i < 10816) { src = W2; off = i - 8256; }
        else                { src = b2; off = i - 10816; }
        wf[i] = isF32 ? ((const float*)src)[off]
                      : __bfloat162float(((bf16p)src)[off]);
    }
}

// ---- Heterogeneous fused kernel: blocks [0,nbin) partition edges into 1024
//      c-contiguous buckets (LDS counters, per-(block,bucket) reservations, no
//      per-edge global atomics); blocks [nbin,nbin+g1) run GEMM1 via MFMA.
//      The two roles are independent (graph chain vs feature chain) and overlap
//      on-device: bin2 is memory-latency-bound, gemm1 is compute-bound.
//      GEMM1 fragment layout (HW-verified R0):
//        A: lane l, elem j -> A[l&15][(l>>4)*8 + j]
//        B: lane l, elem j -> B[(l>>4)*8 + j][l&15]
//        C: lane l, reg  q -> C[(l>>4)*4 + q][l&15]
__global__ __launch_bounds__(256) void k_bin_gemm1(const int* ei, const int* flags,
        int* bincnt2, long long* bins2, int E, int N, float invNB, int nbin,
        const void* x, const float* W1f, __hip_bfloat16* h1b, int g1) {
    __shared__ __align__(16) unsigned char smem[16384];

    if (blockIdx.x < nbin) {
        // ================= bin2 role =================
        int* cnt  = (int*)smem;            // 1024 ints
        int* base = (int*)(smem + 4096);   // 1024 ints
        for (int i = threadIdx.x; i < NBUCK; i += 256) cnt[i] = 0;
        __syncthreads();
        const int i64 = flags[1];
        const int e0 = blockIdx.x * 4096;
        const int e1 = min(e0 + 4096, E);
        int e = e0 + threadIdx.x;
        for (; e + 3 * 256 < e1; e += 4 * 256) {   // 4 independent loads in flight
            int c0 = i64 ? ei[2 * (E + e)]       : ei[E + e];
            int c1 = i64 ? ei[2 * (E + e + 256)] : ei[E + e + 256];
            int c2 = i64 ? ei[2 * (E + e + 512)] : ei[E + e + 512];
            int c3 = i64 ? ei[2 * (E + e + 768)] : ei[E + e + 768];
            atomicAdd(&cnt[bucket_of(c0, N, invNB)], 1);
            atomicAdd(&cnt[bucket_of(c1, N, invNB)], 1);
            atomicAdd(&cnt[bucket_of(c2, N, invNB)], 1);
            atomicAdd(&cnt[bucket_of(c3, N, invNB)], 1);
        }
        for (; e < e1; e += 256) {
            int c = i64 ? ei[2 * (E + e)] : ei[E + e];
            atomicAdd(&cnt[bucket_of(c, N, invNB)], 1);
        }
        __syncthreads();
        for (int i = threadIdx.x; i < NBUCK; i += 256) {
            int v = cnt[i];
            base[i] = v ? atomicAdd(&bincnt2[i], v) : 0;
            cnt[i] = 0;   // reuse as within-block cursor
        }
        __syncthreads();
        for (e = e0 + threadIdx.x; e < e1; e += 256) {  // chunk is L2-hot now
            int r, c;
            if (i64) { r = ei[2 * e]; c = ei[2 * (E + e)]; }
            else     { r = ei[e];     c = ei[E + e]; }
            int b = bucket_of(c, N, invNB);
            int slot = base[b] + atomicAdd(&cnt[b], 1);
            if (slot < CAP2)   // memory safety; never triggers at 2x margin
                bins2[(size_t)b * CAP2 + slot] = ((long long)r << 32) | (unsigned int)c;
        }
        return;
    }

    // ================= gemm1 role =================
    unsigned short (*wT)[IN_CH] = (unsigned short(*)[IN_CH])smem;   // W1^T bf16, 16 KB
    for (int i = threadIdx.x; i < IN_CH * HID; i += 256) {
        int k = i >> 6, c = i & 63;
        __hip_bfloat16 b = __float2bfloat16(W1f[i]);
        wT[c][k] = *reinterpret_cast<unsigned short*>(&b);
    }
    __syncthreads();

    const int isF32 = flags[0];
    const int lane = threadIdx.x & 63;
    const int wid  = threadIdx.x >> 6;
    const int r = lane & 15;     // A row / B col / C col within tile
    const int g = lane >> 4;     // k-group
    const int bb = blockIdx.x - nbin;

    bf16x8 bfr[4][4];
    #pragma unroll
    for (int nt = 0; nt < 4; ++nt)
        #pragma unroll
        for (int ks = 0; ks < 4; ++ks)
            bfr[nt][ks] = *(const bf16x8*)&wT[nt * 16 + r][ks * 32 + g * 8];

    const int tiles = (N + 15) >> 4;
    for (int t = bb * 4 + wid; t < tiles; t += g1 * 4) {
        const int row0 = t * 16;
        int arow = row0 + r; if (arow >= N) arow = N - 1;   // clamp (stores guarded)
        bf16x8 afr[4];
        if (!isF32) {
            const unsigned short* xr = (const unsigned short*)x + (size_t)arow * IN_CH;
            #pragma unroll
            for (int ks = 0; ks < 4; ++ks)
                afr[ks] = *(const bf16x8*)&xr[ks * 32 + g * 8];
        } else {
            // vectorized f32 path: 2x f32x4 (16B) loads per ks, then pack to bf16
            const float* xr = (const float*)x + (size_t)arow * IN_CH;
            #pragma unroll
            for (int ks = 0; ks < 4; ++ks) {
                f32x4 a0 = *(const f32x4*)&xr[ks * 32 + g * 8];
                f32x4 a1 = *(const f32x4*)&xr[ks * 32 + g * 8 + 4];
                #pragma unroll
                for (int j = 0; j < 4; ++j) {
                    __hip_bfloat16 b0 = __float2bfloat16(a0[j]);
                    __hip_bfloat16 b1v = __float2bfloat16(a1[j]);
                    afr[ks][j]     = *reinterpret_cast<short*>(&b0);
                    afr[ks][j + 4] = *reinterpret_cast<short*>(&b1v);
                }
            }
        }
        f32x4 acc[4] = {};
        #pragma unroll
        for (int ks = 0; ks < 4; ++ks)
            #pragma unroll
            for (int nt = 0; nt < 4; ++nt)
                acc[nt] = __builtin_amdgcn_mfma_f32_16x16x32_bf16(afr[ks], bfr[nt][ks],
                                                                  acc[nt], 0, 0, 0);
        #pragma unroll
        for (int nt = 0; nt < 4; ++nt) {
            #pragma unroll
            for (int q = 0; q < 4; ++q) {
                int rr = row0 + g * 4 + q;
                if (rr < N)
                    h1b[(size_t)rr * HID + nt * 16 + r] = __float2bfloat16(acc[nt][q]);
            }
        }
    }
}

// ---- Per-bucket CSR finalize, entirely in LDS (no global atomics). The bucket's
//      global erow base is computed in-block (reduce over bincnt2[0..s)).
//      Buckets are c-contiguous so bucket CSR slices concatenate:
//      rowstart[c] = gb + local_excl_scan; dinv computed here too.
__global__ __launch_bounds__(256) void k_csr(const long long* bins2, const int* bincnt2,
        int* rowstart, float* dinv, int* erow, int N) {
    __shared__ long long rc[CAPL];                 // 20 KB
    __shared__ int sdeg[256], lcur[256], red[256];
    const int s = blockIdx.x;
    const int tid = threadIdx.x;
    // gb = sum_{j<s} min(bincnt2[j], CAPL)
    int part = 0;
    for (int j = tid; j < s; j += 256) part += min(bincnt2[j], CAPL);
    red[tid] = part;
    __syncthreads();
    for (int o = 128; o > 0; o >>= 1) {
        if (tid < o) red[tid] += red[tid + o];
        __syncthreads();
    }
    const int gb = red[0];
    const int nlo = (int)(((long long)s * N + NBUCK - 1) >> NBSHIFT);
    const int nhi = (int)(((long long)(s + 1) * N + NBUCK - 1) >> NBSHIFT);
    const int width = nhi - nlo;                   // <= 98 for N=100000
    const int cnt = min(bincnt2[s], CAPL);

    for (int i = tid; i < cnt; i += 256) rc[i] = bins2[(size_t)s * CAP2 + i];
    sdeg[tid] = 0;
    __syncthreads();
    for (int i = tid; i < cnt; i += 256) {
        int j = (int)(rc[i] & 0xffffffffLL) - nlo;
        if (j >= 0 && j < width) atomicAdd(&sdeg[j], 1);
    }
    __syncthreads();
    int my = sdeg[tid];
    __syncthreads();
    for (int off = 1; off < 256; off <<= 1) {      // inclusive scan of sdeg
        int t = (tid >= off) ? sdeg[tid - off] : 0;
        __syncthreads();
        sdeg[tid] += t;
        __syncthreads();
    }
    int excl = sdeg[tid] - my;
    lcur[tid] = excl;
    if (tid < width) {
        rowstart[nlo + tid] = gb + excl;
        dinv[nlo + tid] = rsqrtf((float)my + 1.0f);   // +1 = self-loop
    }
    if (s == NBUCK - 1 && tid == 0) rowstart[N] = gb + cnt;
    __syncthreads();
    for (int i = tid; i < cnt; i += 256) {
        long long v = rc[i];
        int j = (int)(v & 0xffffffffLL) - nlo;
        if (j >= 0 && j < width) {
            int pos = atomicAdd(&lcur[j], 1);
            erow[gb + pos] = (int)(v >> 32);   // random 4B within ~6KB L2 region
        }
    }
}

// ---- Pure aggregation 1: g[w] = relu(d^2*h1[w] + sum_e n*h1[r] + b1), bf16 out.
//      Lane = (sub 0..7, co 0..7): bf16x8 (16 B) gathers, 8 edges in flight per
//      load instr, x2 unroll. 3-stage shfl_xor cross-sub reduce. (At the measured
//      gather floor: FETCH ~ 8 XCDs x full h1b; structural for random graphs.)
__global__ __launch_bounds__(256) void k_agg1(const int* rowstart, const int* erow,
        const __hip_bfloat16* h1b, const float* dinv, const float* b1f,
        __hip_bfloat16* g, int N) {
    const int lane = threadIdx.x & 63;
    const int sub = lane >> 3;
    const int co  = lane & 7;
    const f32x4 b1a = *(const f32x4*)&b1f[co * 8];
    const f32x4 b1b = *(const f32x4*)&b1f[co * 8 + 4];
    const int wstride = (gridDim.x * 256) >> 6;
    for (int w = (blockIdx.x * 256 + threadIdx.x) >> 6; w < N; w += wstride) {
        int s0 = __builtin_amdgcn_readfirstlane(rowstart[w]);
        int s1 = __builtin_amdgcn_readfirstlane(rowstart[w + 1]);
        float d = dinv[w];
        bf16x8 sv = *(const bf16x8*)&h1b[(size_t)w * HID + co * 8];
        f32x8 acc = {};
        int i = s0 + sub;
        for (; i + 8 < s1; i += 16) {
            int r0 = erow[i], r1 = erow[i + 8];
            float n0 = dinv[r0] * d, n1 = dinv[r1] * d;
            f32x8 v0 = cvt8(*(const bf16x8*)&h1b[(size_t)r0 * HID + co * 8]);
            f32x8 v1 = cvt8(*(const bf16x8*)&h1b[(size_t)r1 * HID + co * 8]);
            #pragma unroll
            for (int j = 0; j < 8; ++j) {
                acc[j] = fmaf(v0[j], n0, acc[j]);
                acc[j] = fmaf(v1[j], n1, acc[j]);
            }
        }
        if (i < s1) {
            int r0 = erow[i];
            float n0 = dinv[r0] * d;
            f32x8 v0 = cvt8(*(const bf16x8*)&h1b[(size_t)r0 * HID + co * 8]);
            #pragma unroll
            for (int j = 0; j < 8; ++j) acc[j] = fmaf(v0[j], n0, acc[j]);
        }
        #pragma unroll
        for (int j = 0; j < 8; ++j) {
            acc[j] += __shfl_xor(acc[j], 8);
            acc[j] += __shfl_xor(acc[j], 16);
            acc[j] += __shfl_xor(acc[j], 32);
        }
        if (sub == 0) {
            float dd = d * d;
            f32x8 sf = cvt8(sv);
            f32x8 gv;
            #pragma unroll
            for (int j = 0; j < 4; ++j) {
                gv[j]     = fmaxf(fmaf(sf[j], dd, acc[j]) + b1a[j], 0.f);
                gv[j + 4] = fmaxf(fmaf(sf[j + 4], dd, acc[j + 4]) + b1b[j], 0.f);
            }
            *(bf16x8*)&g[(size_t)w * HID + co * 8] = pack8(gv);
        }
    }
}

// ---- Pure aggregation 2: s[w] = d^2*g[w] + sum_e n*g[r], bf16 out (no bias/relu;
//      GEMM2 commutes past aggregation: out = agg(g) @ W2 + b2). Same lane map.
__global__ __launch_bounds__(256) void k_agg2s(const int* rowstart, const int* erow,
        const __hip_bfloat16* g, const float* dinv, __hip_bfloat16* sbuf, int N) {
    const int lane = threadIdx.x & 63;
    const int sub = lane >> 3;
    const int co  = lane & 7;
    const int wstride = (gridDim.x * 256) >> 6;
    for (int w = (blockIdx.x * 256 + threadIdx.x) >> 6; w < N; w += wstride) {
        int s0 = __builtin_amdgcn_readfirstlane(rowstart[w]);
        int s1 = __builtin_amdgcn_readfirstlane(rowstart[w + 1]);
        float d = dinv[w];
        bf16x8 sv = *(const bf16x8*)&g[(size_t)w * HID + co * 8];
        f32x8 acc = {};
        int i = s0 + sub;
        for (; i + 8 < s1; i += 16) {
            int r0 = erow[i], r1 = erow[i + 8];
            float n0 = dinv[r0] * d, n1 = dinv[r1] * d;
            f32x8 v0 = cvt8(*(const bf16x8*)&g[(size_t)r0 * HID + co * 8]);
            f32x8 v1 = cvt8(*(const bf16x8*)&g[(size_t)r1 * HID + co * 8]);
            #pragma unroll
            for (int j = 0; j < 8; ++j) {
                acc[j] = fmaf(v0[j], n0, acc[j]);
                acc[j] = fmaf(v1[j], n1, acc[j]);
            }
        }
        if (i < s1) {
            int r0 = erow[i];
            float n0 = dinv[r0] * d;
            f32x8 v0 = cvt8(*(const bf16x8*)&g[(size_t)r0 * HID + co * 8]);
            #pragma unroll
            for (int j = 0; j < 8; ++j) acc[j] = fmaf(v0[j], n0, acc[j]);
        }
        #pragma unroll
        for (int j = 0; j < 8; ++j) {
            acc[j] += __shfl_xor(acc[j], 8);
            acc[j] += __shfl_xor(acc[j], 16);
            acc[j] += __shfl_xor(acc[j], 32);
        }
        if (sub == 0) {
            float dd = d * d;
            f32x8 sf = cvt8(sv);
            f32x8 ov;
            #pragma unroll
            for (int j = 0; j < 8; ++j) ov[j] = fmaf(sf[j], dd, acc[j]);
            *(bf16x8*)&sbuf[(size_t)w * HID + co * 8] = pack8(ov);
        }
    }
}

// ---- GEMM2 via MFMA: out[n][c] = sum_k s[n][k]*W2[k][c] + b2[c], f32 out.
__global__ __launch_bounds__(256) void k_gemm2_mfma(const __hip_bfloat16* sbuf,
        const float* W2f, const float* b2f, float* out, int N) {
    __shared__ __align__(16) unsigned short w2T[48][HID];   // W2^T padded, bf16 bits, 6 KB
    for (int i = threadIdx.x; i < 48 * HID; i += 256) {
        int c = i >> 6, k = i & 63;
        float v = (c < OUT_CH) ? W2f[k * OUT_CH + c] : 0.f;
        __hip_bfloat16 b = __float2bfloat16(v);
        w2T[c][k] = *reinterpret_cast<unsigned short*>(&b);
    }
    __syncthreads();

    const int lane = threadIdx.x & 63;
    const int wid  = threadIdx.x >> 6;
    const int r = lane & 15;
    const int gq = lane >> 4;

    bf16x8 bfr[3][2];
    #pragma unroll
    for (int nt = 0; nt < 3; ++nt)
        #pragma unroll
        for (int ks = 0; ks < 2; ++ks)
            bfr[nt][ks] = *(const bf16x8*)&w2T[nt * 16 + r][ks * 32 + gq * 8];
    float b2v[3];
    #pragma unroll
    for (int nt = 0; nt < 3; ++nt)
        b2v[nt] = (nt * 16 + r < OUT_CH) ? b2f[nt * 16 + r] : 0.f;

    const int tiles = (N + 15) >> 4;
    for (int t = blockIdx.x * 4 + wid; t < tiles; t += gridDim.x * 4) {
        const int row0 = t * 16;
        int arow = row0 + r; if (arow >= N) arow = N - 1;
        const unsigned short* sr = (const unsigned short*)sbuf + (size_t)arow * HID;
        bf16x8 afr[2];
        afr[0] = *(const bf16x8*)&sr[gq * 8];
        afr[1] = *(const bf16x8*)&sr[32 + gq * 8];
        f32x4 acc[3] = {};
        #pragma unroll
        for (int ks = 0; ks < 2; ++ks)
            #pragma unroll
            for (int nt = 0; nt < 3; ++nt)
                acc[nt] = __builtin_amdgcn_mfma_f32_16x16x32_bf16(afr[ks], bfr[nt][ks],
                                                                  acc[nt], 0, 0, 0);
        #pragma unroll
        for (int nt = 0; nt < 3; ++nt) {
            int c = nt * 16 + r;
            #pragma unroll
            for (int q = 0; q < 4; ++q) {
                int rr = row0 + gq * 4 + q;
                if (rr < N && c < OUT_CH)
                    out[(size_t)rr * OUT_CH + c] = acc[nt][q] + b2v[nt];
            }
        }
    }
}

extern "C" void kernel_launch(void* const* d_in, const int* in_sizes, int n_in,
                              void* d_out, int out_size, void* d_ws, size_t ws_size,
                              hipStream_t stream) {
    const void* x  = d_in[0];
    const void* ei = d_in[1];
    const void* W1 = d_in[2];
    const void* b1 = d_in[3];
    const void* W2 = d_in[4];
    const void* b2 = d_in[5];
    const int N = in_sizes[0] / IN_CH;   // 100000
    const int E = in_sizes[1] / 2;       // 1600000
    const int* eii = (const int*)ei;

    // ---- workspace layout (4-byte units). bins2 aliases h1b+g is NOT possible
    //      anymore (bin2 and gemm1 run concurrently): bins2 gets its own region.
    float* ws = (float*)d_ws;
    size_t off = 16;
    int*   flags    = (int*)ws;
    int*   bincnt2  = (int*)ws + off;            off += NBUCK;
    float* dinv     = ws + off;                  off += N;
    float* wf       = ws + off;                  off += 10880;
    int*   rowstart = (int*)ws + off;            off += N + 1;
    off = (off + 255) & ~(size_t)255;
    int*   erow     = (int*)ws + off;            off += E;
    off = (off + 255) & ~(size_t)255;
    __hip_bfloat16* h1b = (__hip_bfloat16*)(ws + off);     off += (size_t)N * HID / 2;
    __hip_bfloat16* g   = (__hip_bfloat16*)(ws + off);     off += (size_t)N * HID / 2;
    off = (off + 255) & ~(size_t)255;
    long long* bins2 = (long long*)(ws + off);   off += (size_t)NBUCK * CAP2 * 2;  // 25.6MB
    __hip_bfloat16* sbuf = h1b;                  // h1b dead once k_agg1 completes

    k_detectconv<<<1, 256, 0, stream>>>(x, ei, flags, W1, b1, W2, b2, wf, bincnt2);

    float invNB = (float)NBUCK / (float)N;
    int nbin = (E + 4095) / 4096;        // 391 bin-role blocks
    int tiles = (N + 15) / 16;
    int g1 = (tiles + 7) / 8;            // 782 gemm-role blocks (4 waves, 2 tiles/wave)
    k_bin_gemm1<<<nbin + g1, 256, 0, stream>>>(eii, flags, bincnt2, bins2, E, N,
                                               invNB, nbin, x, wf, h1b, g1);
    k_csr<<<NBUCK, 256, 0, stream>>>(bins2, bincnt2, rowstart, dinv, erow, N);

    k_agg1<<<4096, 256, 0, stream>>>(rowstart, erow, h1b, dinv, wf + 8192, g, N);
    k_agg2s<<<4096, 256, 0, stream>>>(rowstart, erow, g, dinv, sbuf, N);
    k_gemm2_mfma<<<g1, 256, 0, stream>>>(sbuf, wf + 8256, wf + 10816, (float*)d_out, N);
}

// Round 11
// 270.949 us; speedup vs baseline: 1.0311x; 1.0311x over previous
//
#include <hip/hip_runtime.h>
#include <hip/hip_bf16.h>
#include <math.h>

#define IN_CH 128
#define HID 64
#define OUT_CH 40
#define NBUCK 1024
#define NBSHIFT 10
#define CAP2 3125     // bins2 slots per bucket (2x mean 1563); 1024*3125*8B = 25.6MB
#define CAPL 2560     // LDS records per bucket in k_csr (~25 sigma above mean)

typedef const __hip_bfloat16* bf16p;
typedef __attribute__((ext_vector_type(8))) short bf16x8;
typedef __attribute__((ext_vector_type(4))) float f32x4;
typedef __attribute__((ext_vector_type(8))) float f32x8;

// bf16 -> f32 is exact: shift into the high half
__device__ __forceinline__ f32x8 cvt8(bf16x8 v) {
    f32x8 o;
    #pragma unroll
    for (int j = 0; j < 8; ++j) {
        unsigned int bits = ((unsigned int)(unsigned short)v[j]) << 16;
        o[j] = __uint_as_float(bits);
    }
    return o;
}

__device__ __forceinline__ bf16x8 pack8(f32x8 v) {
    bf16x8 o;
    #pragma unroll
    for (int j = 0; j < 8; ++j) {
        __hip_bfloat16 b = __float2bfloat16(v[j]);
        o[j] = *reinterpret_cast<short*>(&b);
    }
    return o;
}

// exact bucket of column c: b s.t. b*N <= c*1024 < (b+1)*N. Float approx + exact
// 64-bit-mul fixup (no divide; fixup loops run <=1 iteration).
__device__ __forceinline__ int bucket_of(int c, int N, float invNB) {
    int b = (int)((float)c * invNB);
    long long cB = (long long)c << NBSHIFT;
    while ((long long)(b + 1) * N <= cB) ++b;
    while (b > 0 && (long long)b * N > cB) --b;
    return b;
}

// ---- fused flag detection + weight conversion + bincnt2 zeroing (1 block).
__global__ __launch_bounds__(256) void k_detectconv(const void* x, const void* ei,
        int* flags, const void* W1, const void* b1, const void* W2, const void* b2,
        float* wf, int* bincnt2) {
    __shared__ int s_f32, s_hi;
    if (threadIdx.x == 0) { s_f32 = 0; s_hi = 0; }
    __syncthreads();
    const __hip_bfloat16* xb = (const __hip_bfloat16*)x;
    const int* ii = (const int*)ei;
    int lf = 0, lh = 0;
    for (int i = threadIdx.x; i < 4096; i += 256) {
        float f = __bfloat162float(xb[i]);
        if (!(fabsf(f) <= 1e4f)) lf = 1;       // huge/NaN -> buffer is really f32
        lh |= ii[2 * i + 1];                    // int64 high words are all zero
    }
    if (lf) atomicOr(&s_f32, 1);
    if (lh) atomicOr(&s_hi, 1);
    for (int i = threadIdx.x; i < NBUCK; i += 256) bincnt2[i] = 0;
    __syncthreads();
    const int isF32 = s_f32 ? 1 : 0;
    if (threadIdx.x == 0) {
        flags[0] = isF32;
        flags[1] = (s_hi == 0) ? 1 : 0;
        flags[2] = 0;
    }
    for (int i = threadIdx.x; i < 10856; i += 256) {
        const void* src; int off;
        if (i < 8192)       { src = W1; off = i; }
        else if (i < 8256)  { src = b1; off = i - 8192; }
        else if (i < 10816) { src = W2; off = i - 8256; }
        else                { src = b2; off = i - 10816; }
        wf[i] = isF32 ? ((const float*)src)[off]
                      : __bfloat162float(((bf16p)src)[off]);
    }
}

// ---- Partition edges into 1024 c-contiguous buckets. No per-edge global atomics:
//      LDS counters + per-(block,bucket) global cursor reservations. 512 threads,
//      pass-1 unrolled x4 so 4 independent loads precede their LDS atomics.
//      (Separate kernel on purpose: fusing with gemm1 unioned regalloc to 72 VGPR
//      and cut occupancy to 23% -- measured regression in R10.)
__global__ __launch_bounds__(512) void k_bin2(const int* ei, const int* flags,
        int* bincnt2, long long* bins2, int E, int N, float invNB) {
    __shared__ int cnt[NBUCK], base[NBUCK];
    for (int i = threadIdx.x; i < NBUCK; i += 512) cnt[i] = 0;
    __syncthreads();
    const int i64 = flags[1];
    const int e0 = blockIdx.x * 4096;
    const int e1 = min(e0 + 4096, E);
    int e = e0 + threadIdx.x;
    for (; e + 3 * 512 < e1; e += 4 * 512) {
        int c0 = i64 ? ei[2 * (E + e)]        : ei[E + e];
        int c1 = i64 ? ei[2 * (E + e + 512)]  : ei[E + e + 512];
        int c2 = i64 ? ei[2 * (E + e + 1024)] : ei[E + e + 1024];
        int c3 = i64 ? ei[2 * (E + e + 1536)] : ei[E + e + 1536];
        atomicAdd(&cnt[bucket_of(c0, N, invNB)], 1);
        atomicAdd(&cnt[bucket_of(c1, N, invNB)], 1);
        atomicAdd(&cnt[bucket_of(c2, N, invNB)], 1);
        atomicAdd(&cnt[bucket_of(c3, N, invNB)], 1);
    }
    for (; e < e1; e += 512) {
        int c = i64 ? ei[2 * (E + e)] : ei[E + e];
        atomicAdd(&cnt[bucket_of(c, N, invNB)], 1);
    }
    __syncthreads();
    for (int i = threadIdx.x; i < NBUCK; i += 512) {
        int v = cnt[i];
        base[i] = v ? atomicAdd(&bincnt2[i], v) : 0;
        cnt[i] = 0;   // reuse as within-block cursor
    }
    __syncthreads();
    for (e = e0 + threadIdx.x; e < e1; e += 512) {  // chunk is L2-hot now
        int r, c;
        if (i64) { r = ei[2 * e]; c = ei[2 * (E + e)]; }
        else     { r = ei[e];     c = ei[E + e]; }
        int b = bucket_of(c, N, invNB);
        int slot = base[b] + atomicAdd(&cnt[b], 1);
        if (slot < CAP2)   // memory safety; never triggers at 2x margin
            bins2[(size_t)b * CAP2 + slot] = ((long long)r << 32) | (unsigned int)c;
    }
}

// ---- Per-bucket CSR finalize, entirely in LDS (no global atomics). The bucket's
//      global erow base is computed in-block (reduce over bincnt2[0..s)).
//      Buckets are c-contiguous so bucket CSR slices concatenate:
//      rowstart[c] = gb + local_excl_scan; dinv computed here too.
__global__ __launch_bounds__(256) void k_csr(const long long* bins2, const int* bincnt2,
        int* rowstart, float* dinv, int* erow, int N) {
    __shared__ long long rc[CAPL];                 // 20 KB
    __shared__ int sdeg[256], lcur[256], red[256];
    const int s = blockIdx.x;
    const int tid = threadIdx.x;
    // gb = sum_{j<s} min(bincnt2[j], CAPL)
    int part = 0;
    for (int j = tid; j < s; j += 256) part += min(bincnt2[j], CAPL);
    red[tid] = part;
    __syncthreads();
    for (int o = 128; o > 0; o >>= 1) {
        if (tid < o) red[tid] += red[tid + o];
        __syncthreads();
    }
    const int gb = red[0];
    const int nlo = (int)(((long long)s * N + NBUCK - 1) >> NBSHIFT);
    const int nhi = (int)(((long long)(s + 1) * N + NBUCK - 1) >> NBSHIFT);
    const int width = nhi - nlo;                   // <= 98 for N=100000
    const int cnt = min(bincnt2[s], CAPL);

    for (int i = tid; i < cnt; i += 256) rc[i] = bins2[(size_t)s * CAP2 + i];
    sdeg[tid] = 0;
    __syncthreads();
    for (int i = tid; i < cnt; i += 256) {
        int j = (int)(rc[i] & 0xffffffffLL) - nlo;
        if (j >= 0 && j < width) atomicAdd(&sdeg[j], 1);
    }
    __syncthreads();
    int my = sdeg[tid];
    __syncthreads();
    for (int off = 1; off < 256; off <<= 1) {      // inclusive scan of sdeg
        int t = (tid >= off) ? sdeg[tid - off] : 0;
        __syncthreads();
        sdeg[tid] += t;
        __syncthreads();
    }
    int excl = sdeg[tid] - my;
    lcur[tid] = excl;
    if (tid < width) {
        rowstart[nlo + tid] = gb + excl;
        dinv[nlo + tid] = rsqrtf((float)my + 1.0f);   // +1 = self-loop
    }
    if (s == NBUCK - 1 && tid == 0) rowstart[N] = gb + cnt;
    __syncthreads();
    for (int i = tid; i < cnt; i += 256) {
        long long v = rc[i];
        int j = (int)(v & 0xffffffffLL) - nlo;
        if (j >= 0 && j < width) {
            int pos = atomicAdd(&lcur[j], 1);
            erow[gb + pos] = (int)(v >> 32);   // random 4B within ~6KB L2 region
        }
    }
}

// ---- GEMM1 via MFMA (HW-verified in R0): h1b[n][c] = bf16(sum_k x[n][k]*W1[k][c])
//      A: lane l, elem j -> A[l&15][(l>>4)*8 + j]
//      B: lane l, elem j -> B[(l>>4)*8 + j][l&15]
//      C: lane l, reg  q -> C[(l>>4)*4 + q][l&15]
//      f32 path vectorized: 2x f32x4 (16B) loads per ks (was 32 scalar loads/lane).
__global__ __launch_bounds__(256) void k_gemm1_mfma(const void* x, const float* W1f,
        __hip_bfloat16* h1b, const int* flags, int N) {
    __shared__ __align__(16) unsigned short wT[HID][IN_CH];   // W1^T, bf16 bits, 16 KB
    for (int i = threadIdx.x; i < IN_CH * HID; i += 256) {
        int k = i >> 6, c = i & 63;
        __hip_bfloat16 b = __float2bfloat16(W1f[i]);
        wT[c][k] = *reinterpret_cast<unsigned short*>(&b);
    }
    __syncthreads();

    const int isF32 = flags[0];
    const int lane = threadIdx.x & 63;
    const int wid  = threadIdx.x >> 6;
    const int r = lane & 15;     // A row / B col / C col within tile
    const int g = lane >> 4;     // k-group

    bf16x8 bfr[4][4];
    #pragma unroll
    for (int nt = 0; nt < 4; ++nt)
        #pragma unroll
        for (int ks = 0; ks < 4; ++ks)
            bfr[nt][ks] = *(const bf16x8*)&wT[nt * 16 + r][ks * 32 + g * 8];

    const int tiles = (N + 15) >> 4;
    for (int t = blockIdx.x * 4 + wid; t < tiles; t += gridDim.x * 4) {
        const int row0 = t * 16;
        int arow = row0 + r; if (arow >= N) arow = N - 1;   // clamp (stores guarded)
        bf16x8 afr[4];
        if (!isF32) {
            const unsigned short* xr = (const unsigned short*)x + (size_t)arow * IN_CH;
            #pragma unroll
            for (int ks = 0; ks < 4; ++ks)
                afr[ks] = *(const bf16x8*)&xr[ks * 32 + g * 8];
        } else {
            const float* xr = (const float*)x + (size_t)arow * IN_CH;
            #pragma unroll
            for (int ks = 0; ks < 4; ++ks) {
                f32x4 a0 = *(const f32x4*)&xr[ks * 32 + g * 8];
                f32x4 a1 = *(const f32x4*)&xr[ks * 32 + g * 8 + 4];
                #pragma unroll
                for (int j = 0; j < 4; ++j) {
                    __hip_bfloat16 b0 = __float2bfloat16(a0[j]);
                    __hip_bfloat16 b1v = __float2bfloat16(a1[j]);
                    afr[ks][j]     = *reinterpret_cast<short*>(&b0);
                    afr[ks][j + 4] = *reinterpret_cast<short*>(&b1v);
                }
            }
        }
        f32x4 acc[4] = {};
        #pragma unroll
        for (int ks = 0; ks < 4; ++ks)
            #pragma unroll
            for (int nt = 0; nt < 4; ++nt)
                acc[nt] = __builtin_amdgcn_mfma_f32_16x16x32_bf16(afr[ks], bfr[nt][ks],
                                                                  acc[nt], 0, 0, 0);
        #pragma unroll
        for (int nt = 0; nt < 4; ++nt) {
            #pragma unroll
            for (int q = 0; q < 4; ++q) {
                int rr = row0 + g * 4 + q;
                if (rr < N)
                    h1b[(size_t)rr * HID + nt * 16 + r] = __float2bfloat16(acc[nt][q]);
            }
        }
    }
}

// ---- Pure aggregation 1: g[w] = relu(d^2*h1[w] + sum_e n*h1[r] + b1), bf16 out.
//      Lane = (sub 0..7, co 0..7): bf16x8 (16 B) gathers, 8 edges in flight per
//      load instr, x2 unroll. 3-stage shfl_xor cross-sub reduce. (At the measured
//      gather floor: FETCH ~ 8 XCDs x full h1b; structural for random graphs.)
__global__ __launch_bounds__(256) void k_agg1(const int* rowstart, const int* erow,
        const __hip_bfloat16* h1b, const float* dinv, const float* b1f,
        __hip_bfloat16* g, int N) {
    const int lane = threadIdx.x & 63;
    const int sub = lane >> 3;
    const int co  = lane & 7;
    const f32x4 b1a = *(const f32x4*)&b1f[co * 8];
    const f32x4 b1b = *(const f32x4*)&b1f[co * 8 + 4];
    const int wstride = (gridDim.x * 256) >> 6;
    for (int w = (blockIdx.x * 256 + threadIdx.x) >> 6; w < N; w += wstride) {
        int s0 = __builtin_amdgcn_readfirstlane(rowstart[w]);
        int s1 = __builtin_amdgcn_readfirstlane(rowstart[w + 1]);
        float d = dinv[w];
        bf16x8 sv = *(const bf16x8*)&h1b[(size_t)w * HID + co * 8];
        f32x8 acc = {};
        int i = s0 + sub;
        for (; i + 8 < s1; i += 16) {
            int r0 = erow[i], r1 = erow[i + 8];
            float n0 = dinv[r0] * d, n1 = dinv[r1] * d;
            f32x8 v0 = cvt8(*(const bf16x8*)&h1b[(size_t)r0 * HID + co * 8]);
            f32x8 v1 = cvt8(*(const bf16x8*)&h1b[(size_t)r1 * HID + co * 8]);
            #pragma unroll
            for (int j = 0; j < 8; ++j) {
                acc[j] = fmaf(v0[j], n0, acc[j]);
                acc[j] = fmaf(v1[j], n1, acc[j]);
            }
        }
        if (i < s1) {
            int r0 = erow[i];
            float n0 = dinv[r0] * d;
            f32x8 v0 = cvt8(*(const bf16x8*)&h1b[(size_t)r0 * HID + co * 8]);
            #pragma unroll
            for (int j = 0; j < 8; ++j) acc[j] = fmaf(v0[j], n0, acc[j]);
        }
        #pragma unroll
        for (int j = 0; j < 8; ++j) {
            acc[j] += __shfl_xor(acc[j], 8);
            acc[j] += __shfl_xor(acc[j], 16);
            acc[j] += __shfl_xor(acc[j], 32);
        }
        if (sub == 0) {
            float dd = d * d;
            f32x8 sf = cvt8(sv);
            f32x8 gv;
            #pragma unroll
            for (int j = 0; j < 4; ++j) {
                gv[j]     = fmaxf(fmaf(sf[j], dd, acc[j]) + b1a[j], 0.f);
                gv[j + 4] = fmaxf(fmaf(sf[j + 4], dd, acc[j + 4]) + b1b[j], 0.f);
            }
            *(bf16x8*)&g[(size_t)w * HID + co * 8] = pack8(gv);
        }
    }
}

// ---- Pure aggregation 2: s[w] = d^2*g[w] + sum_e n*g[r], bf16 out (no bias/relu;
//      GEMM2 commutes past aggregation: out = agg(g) @ W2 + b2). Same lane map.
__global__ __launch_bounds__(256) void k_agg2s(const int* rowstart, const int* erow,
        const __hip_bfloat16* g, const float* dinv, __hip_bfloat16* sbuf, int N) {
    const int lane = threadIdx.x & 63;
    const int sub = lane >> 3;
    const int co  = lane & 7;
    const int wstride = (gridDim.x * 256) >> 6;
    for (int w = (blockIdx.x * 256 + threadIdx.x) >> 6; w < N; w += wstride) {
        int s0 = __builtin_amdgcn_readfirstlane(rowstart[w]);
        int s1 = __builtin_amdgcn_readfirstlane(rowstart[w + 1]);
        float d = dinv[w];
        bf16x8 sv = *(const bf16x8*)&g[(size_t)w * HID + co * 8];
        f32x8 acc = {};
        int i = s0 + sub;
        for (; i + 8 < s1; i += 16) {
            int r0 = erow[i], r1 = erow[i + 8];
            float n0 = dinv[r0] * d, n1 = dinv[r1] * d;
            f32x8 v0 = cvt8(*(const bf16x8*)&g[(size_t)r0 * HID + co * 8]);
            f32x8 v1 = cvt8(*(const bf16x8*)&g[(size_t)r1 * HID + co * 8]);
            #pragma unroll
            for (int j = 0; j < 8; ++j) {
                acc[j] = fmaf(v0[j], n0, acc[j]);
                acc[j] = fmaf(v1[j], n1, acc[j]);
            }
        }
        if (i < s1) {
            int r0 = erow[i];
            float n0 = dinv[r0] * d;
            f32x8 v0 = cvt8(*(const bf16x8*)&g[(size_t)r0 * HID + co * 8]);
            #pragma unroll
            for (int j = 0; j < 8; ++j) acc[j] = fmaf(v0[j], n0, acc[j]);
        }
        #pragma unroll
        for (int j = 0; j < 8; ++j) {
            acc[j] += __shfl_xor(acc[j], 8);
            acc[j] += __shfl_xor(acc[j], 16);
            acc[j] += __shfl_xor(acc[j], 32);
        }
        if (sub == 0) {
            float dd = d * d;
            f32x8 sf = cvt8(sv);
            f32x8 ov;
            #pragma unroll
            for (int j = 0; j < 8; ++j) ov[j] = fmaf(sf[j], dd, acc[j]);
            *(bf16x8*)&sbuf[(size_t)w * HID + co * 8] = pack8(ov);
        }
    }
}

// ---- GEMM2 via MFMA: out[n][c] = sum_k s[n][k]*W2[k][c] + b2[c], f32 out.
__global__ __launch_bounds__(256) void k_gemm2_mfma(const __hip_bfloat16* sbuf,
        const float* W2f, const float* b2f, float* out, int N) {
    __shared__ __align__(16) unsigned short w2T[48][HID];   // W2^T padded, bf16 bits, 6 KB
    for (int i = threadIdx.x; i < 48 * HID; i += 256) {
        int c = i >> 6, k = i & 63;
        float v = (c < OUT_CH) ? W2f[k * OUT_CH + c] : 0.f;
        __hip_bfloat16 b = __float2bfloat16(v);
        w2T[c][k] = *reinterpret_cast<unsigned short*>(&b);
    }
    __syncthreads();

    const int lane = threadIdx.x & 63;
    const int wid  = threadIdx.x >> 6;
    const int r = lane & 15;
    const int gq = lane >> 4;

    bf16x8 bfr[3][2];
    #pragma unroll
    for (int nt = 0; nt < 3; ++nt)
        #pragma unroll
        for (int ks = 0; ks < 2; ++ks)
            bfr[nt][ks] = *(const bf16x8*)&w2T[nt * 16 + r][ks * 32 + gq * 8];
    float b2v[3];
    #pragma unroll
    for (int nt = 0; nt < 3; ++nt)
        b2v[nt] = (nt * 16 + r < OUT_CH) ? b2f[nt * 16 + r] : 0.f;

    const int tiles = (N + 15) >> 4;
    for (int t = blockIdx.x * 4 + wid; t < tiles; t += gridDim.x * 4) {
        const int row0 = t * 16;
        int arow = row0 + r; if (arow >= N) arow = N - 1;
        const unsigned short* sr = (const unsigned short*)sbuf + (size_t)arow * HID;
        bf16x8 afr[2];
        afr[0] = *(const bf16x8*)&sr[gq * 8];
        afr[1] = *(const bf16x8*)&sr[32 + gq * 8];
        f32x4 acc[3] = {};
        #pragma unroll
        for (int ks = 0; ks < 2; ++ks)
            #pragma unroll
            for (int nt = 0; nt < 3; ++nt)
                acc[nt] = __builtin_amdgcn_mfma_f32_16x16x32_bf16(afr[ks], bfr[nt][ks],
                                                                  acc[nt], 0, 0, 0);
        #pragma unroll
        for (int nt = 0; nt < 3; ++nt) {
            int c = nt * 16 + r;
            #pragma unroll
            for (int q = 0; q < 4; ++q) {
                int rr = row0 + gq * 4 + q;
                if (rr < N && c < OUT_CH)
                    out[(size_t)rr * OUT_CH + c] = acc[nt][q] + b2v[nt];
            }
        }
    }
}

extern "C" void kernel_launch(void* const* d_in, const int* in_sizes, int n_in,
                              void* d_out, int out_size, void* d_ws, size_t ws_size,
                              hipStream_t stream) {
    const void* x  = d_in[0];
    const void* ei = d_in[1];
    const void* W1 = d_in[2];
    const void* b1 = d_in[3];
    const void* W2 = d_in[4];
    const void* b2 = d_in[5];
    const int N = in_sizes[0] / IN_CH;   // 100000
    const int E = in_sizes[1] / 2;       // 1600000
    const int* eii = (const int*)ei;

    // ---- workspace layout (4-byte units). bins2 aliases h1b+g again (bin2->csr
    //      complete before gemm1 writes h1b on the serial stream).
    float* ws = (float*)d_ws;
    size_t off = 16;
    int*   flags    = (int*)ws;
    int*   bincnt2  = (int*)ws + off;            off += NBUCK;
    float* dinv     = ws + off;                  off += N;
    float* wf       = ws + off;                  off += 10880;
    int*   rowstart = (int*)ws + off;            off += N + 1;
    off = (off + 255) & ~(size_t)255;
    int*   erow     = (int*)ws + off;            off += E;
    off = (off + 255) & ~(size_t)255;
    __hip_bfloat16* h1b = (__hip_bfloat16*)(ws + off);     off += (size_t)N * HID / 2;
    __hip_bfloat16* g   = (__hip_bfloat16*)(ws + off);     off += (size_t)N * HID / 2;
    __hip_bfloat16* sbuf = h1b;                  // h1b dead once k_agg1 completes
    long long* bins2 = (long long*)h1b;          // 1024*3125*8B = 25.6MB = h1b+g

    k_detectconv<<<1, 256, 0, stream>>>(x, ei, flags, W1, b1, W2, b2, wf, bincnt2);

    float invNB = (float)NBUCK / (float)N;
    int nbin = (E + 4095) / 4096;        // 391 blocks x 512 threads
    k_bin2<<<nbin, 512, 0, stream>>>(eii, flags, bincnt2, bins2, E, N, invNB);
    k_csr<<<NBUCK, 256, 0, stream>>>(bins2, bincnt2, rowstart, dinv, erow, N);

    int tiles = (N + 15) / 16;
    int g1 = (tiles + 7) / 8;           // 4 waves/block, 2 tiles/wave
    k_gemm1_mfma<<<g1, 256, 0, stream>>>(x, wf, h1b, flags, N);

    k_agg1<<<4096, 256, 0, stream>>>(rowstart, erow, h1b, dinv, wf + 8192, g, N);
    k_agg2s<<<4096, 256, 0, stream>>>(rowstart, erow, g, dinv, sbuf, N);
    k_gemm2_mfma<<<g1, 256, 0, stream>>>(sbuf, wf + 8256, wf + 10816, (float*)d_out, N);
}

// Round 12
// 261.056 us; speedup vs baseline: 1.0702x; 1.0379x over previous
//
#include <hip/hip_runtime.h>
#include <hip/hip_bf16.h>
#include <math.h>

#define IN_CH 128
#define HID 64
#define OUT_CH 40
#define NBUCK 1024
#define NBSHIFT 10
#define CAP2 3125     // bins2 slots per bucket (2x mean 1563); 1024*3125*4B = 12.8MB
#define CAPL 2560     // LDS records per bucket in k_csr (~25 sigma above mean)

typedef const __hip_bfloat16* bf16p;
typedef __attribute__((ext_vector_type(8))) short bf16x8;
typedef __attribute__((ext_vector_type(4))) float f32x4;
typedef __attribute__((ext_vector_type(8))) float f32x8;

// bf16 -> f32 is exact: shift into the high half
__device__ __forceinline__ f32x8 cvt8(bf16x8 v) {
    f32x8 o;
    #pragma unroll
    for (int j = 0; j < 8; ++j) {
        unsigned int bits = ((unsigned int)(unsigned short)v[j]) << 16;
        o[j] = __uint_as_float(bits);
    }
    return o;
}

__device__ __forceinline__ bf16x8 pack8(f32x8 v) {
    bf16x8 o;
    #pragma unroll
    for (int j = 0; j < 8; ++j) {
        __hip_bfloat16 b = __float2bfloat16(v[j]);
        o[j] = *reinterpret_cast<short*>(&b);
    }
    return o;
}

// exact bucket of column c: b s.t. b*N <= c*1024 < (b+1)*N. Float approx + exact
// 64-bit-mul fixup (no divide; fixup loops run <=1 iteration).
__device__ __forceinline__ int bucket_of(int c, int N, float invNB) {
    int b = (int)((float)c * invNB);
    long long cB = (long long)c << NBSHIFT;
    while ((long long)(b + 1) * N <= cB) ++b;
    while (b > 0 && (long long)b * N > cB) --b;
    return b;
}

// ---- fused flag detection + weight conversion + bincnt2 zeroing (1 block).
__global__ __launch_bounds__(256) void k_detectconv(const void* x, const void* ei,
        int* flags, const void* W1, const void* b1, const void* W2, const void* b2,
        float* wf, int* bincnt2) {
    __shared__ int s_f32, s_hi;
    if (threadIdx.x == 0) { s_f32 = 0; s_hi = 0; }
    __syncthreads();
    const __hip_bfloat16* xb = (const __hip_bfloat16*)x;
    const int* ii = (const int*)ei;
    int lf = 0, lh = 0;
    for (int i = threadIdx.x; i < 4096; i += 256) {
        float f = __bfloat162float(xb[i]);
        if (!(fabsf(f) <= 1e4f)) lf = 1;       // huge/NaN -> buffer is really f32
        lh |= ii[2 * i + 1];                    // int64 high words are all zero
    }
    if (lf) atomicOr(&s_f32, 1);
    if (lh) atomicOr(&s_hi, 1);
    for (int i = threadIdx.x; i < NBUCK; i += 256) bincnt2[i] = 0;
    __syncthreads();
    const int isF32 = s_f32 ? 1 : 0;
    if (threadIdx.x == 0) {
        flags[0] = isF32;
        flags[1] = (s_hi == 0) ? 1 : 0;
        flags[2] = 0;
    }
    for (int i = threadIdx.x; i < 10856; i += 256) {
        const void* src; int off;
        if (i < 8192)       { src = W1; off = i; }
        else if (i < 8256)  { src = b1; off = i - 8192; }
        else if (i < 10816) { src = W2; off = i - 8256; }
        else                { src = b2; off = i - 10816; }
        wf[i] = isF32 ? ((const float*)src)[off]
                      : __bfloat162float(((bf16p)src)[off]);
    }
}

// ---- Partition edges into 1024 c-contiguous buckets. No per-edge global atomics.
//      Records packed to 4 B: (r << 7) | (c - nlo_bucket); bucket width <= 98 < 128
//      for N=100000, halving bins2 write+read traffic vs 8 B records.
__global__ __launch_bounds__(512) void k_bin2(const int* ei, const int* flags,
        int* bincnt2, unsigned int* bins2, int E, int N, float invNB) {
    __shared__ int cnt[NBUCK], base[NBUCK];
    for (int i = threadIdx.x; i < NBUCK; i += 512) cnt[i] = 0;
    __syncthreads();
    const int i64 = flags[1];
    const int e0 = blockIdx.x * 4096;
    const int e1 = min(e0 + 4096, E);
    int e = e0 + threadIdx.x;
    for (; e + 3 * 512 < e1; e += 4 * 512) {
        int c0 = i64 ? ei[2 * (E + e)]        : ei[E + e];
        int c1 = i64 ? ei[2 * (E + e + 512)]  : ei[E + e + 512];
        int c2 = i64 ? ei[2 * (E + e + 1024)] : ei[E + e + 1024];
        int c3 = i64 ? ei[2 * (E + e + 1536)] : ei[E + e + 1536];
        atomicAdd(&cnt[bucket_of(c0, N, invNB)], 1);
        atomicAdd(&cnt[bucket_of(c1, N, invNB)], 1);
        atomicAdd(&cnt[bucket_of(c2, N, invNB)], 1);
        atomicAdd(&cnt[bucket_of(c3, N, invNB)], 1);
    }
    for (; e < e1; e += 512) {
        int c = i64 ? ei[2 * (E + e)] : ei[E + e];
        atomicAdd(&cnt[bucket_of(c, N, invNB)], 1);
    }
    __syncthreads();
    for (int i = threadIdx.x; i < NBUCK; i += 512) {
        int v = cnt[i];
        base[i] = v ? atomicAdd(&bincnt2[i], v) : 0;
        cnt[i] = 0;   // reuse as within-block cursor
    }
    __syncthreads();
    for (e = e0 + threadIdx.x; e < e1; e += 512) {  // chunk is L2-hot now
        int r, c;
        if (i64) { r = ei[2 * e]; c = ei[2 * (E + e)]; }
        else     { r = ei[e];     c = ei[E + e]; }
        int b = bucket_of(c, N, invNB);
        int nlo = (int)(((long long)b * N + NBUCK - 1) >> NBSHIFT);
        int slot = base[b] + atomicAdd(&cnt[b], 1);
        if (slot < CAP2)   // memory safety; never triggers at 2x margin
            bins2[(size_t)b * CAP2 + slot] =
                ((unsigned int)r << 7) | (unsigned int)(c - nlo);
    }
}

// ---- Per-bucket CSR finalize, entirely in LDS (no global atomics). The bucket's
//      global erow base is computed in-block (reduce over bincnt2[0..s)).
//      Buckets are c-contiguous so bucket CSR slices concatenate:
//      rowstart[c] = gb + local_excl_scan; dinv computed here too.
__global__ __launch_bounds__(256) void k_csr(const unsigned int* bins2, const int* bincnt2,
        int* rowstart, float* dinv, int* erow, int N) {
    __shared__ unsigned int rc[CAPL];              // 10 KB
    __shared__ int sdeg[256], lcur[256], red[256];
    const int s = blockIdx.x;
    const int tid = threadIdx.x;
    // gb = sum_{j<s} min(bincnt2[j], CAPL)
    int part = 0;
    for (int j = tid; j < s; j += 256) part += min(bincnt2[j], CAPL);
    red[tid] = part;
    __syncthreads();
    for (int o = 128; o > 0; o >>= 1) {
        if (tid < o) red[tid] += red[tid + o];
        __syncthreads();
    }
    const int gb = red[0];
    const int nlo = (int)(((long long)s * N + NBUCK - 1) >> NBSHIFT);
    const int nhi = (int)(((long long)(s + 1) * N + NBUCK - 1) >> NBSHIFT);
    const int width = nhi - nlo;                   // <= 98 for N=100000
    const int cnt = min(bincnt2[s], CAPL);

    for (int i = tid; i < cnt; i += 256) rc[i] = bins2[(size_t)s * CAP2 + i];
    sdeg[tid] = 0;
    __syncthreads();
    for (int i = tid; i < cnt; i += 256) {
        int j = (int)(rc[i] & 127u);
        if (j < width) atomicAdd(&sdeg[j], 1);
    }
    __syncthreads();
    int my = sdeg[tid];
    __syncthreads();
    for (int off = 1; off < 256; off <<= 1) {      // inclusive scan of sdeg
        int t = (tid >= off) ? sdeg[tid - off] : 0;
        __syncthreads();
        sdeg[tid] += t;
        __syncthreads();
    }
    int excl = sdeg[tid] - my;
    lcur[tid] = excl;
    if (tid < width) {
        rowstart[nlo + tid] = gb + excl;
        dinv[nlo + tid] = rsqrtf((float)my + 1.0f);   // +1 = self-loop
    }
    if (s == NBUCK - 1 && tid == 0) rowstart[N] = gb + cnt;
    __syncthreads();
    for (int i = tid; i < cnt; i += 256) {
        unsigned int v = rc[i];
        int j = (int)(v & 127u);
        if (j < width) {
            int pos = atomicAdd(&lcur[j], 1);
            erow[gb + pos] = (int)(v >> 7);   // random 4B within ~6KB L2 region
        }
    }
}

// ---- GEMM1 via MFMA (HW-verified R0), now storing PRE-SCALED features:
//      h1s[n][c] = bf16( (sum_k x[n][k]*W1[k][c]) * dinv[n] ).
//      Pre-scaling by the source's dinv removes the per-edge dinv[r] gather
//      (the middle hop of agg1's erow->dinv->h1b dependent chain).
//      A: lane l, elem j -> A[l&15][(l>>4)*8 + j]
//      B: lane l, elem j -> B[(l>>4)*8 + j][l&15]
//      C: lane l, reg  q -> C[(l>>4)*4 + q][l&15]
__global__ __launch_bounds__(256) void k_gemm1_mfma(const void* x, const float* W1f,
        const float* dinv, __hip_bfloat16* h1s, const int* flags, int N) {
    __shared__ __align__(16) unsigned short wT[HID][IN_CH];   // W1^T, bf16 bits, 16 KB
    for (int i = threadIdx.x; i < IN_CH * HID; i += 256) {
        int k = i >> 6, c = i & 63;
        __hip_bfloat16 b = __float2bfloat16(W1f[i]);
        wT[c][k] = *reinterpret_cast<unsigned short*>(&b);
    }
    __syncthreads();

    const int isF32 = flags[0];
    const int lane = threadIdx.x & 63;
    const int wid  = threadIdx.x >> 6;
    const int r = lane & 15;     // A row / B col / C col within tile
    const int g = lane >> 4;     // k-group

    bf16x8 bfr[4][4];
    #pragma unroll
    for (int nt = 0; nt < 4; ++nt)
        #pragma unroll
        for (int ks = 0; ks < 4; ++ks)
            bfr[nt][ks] = *(const bf16x8*)&wT[nt * 16 + r][ks * 32 + g * 8];

    const int tiles = (N + 15) >> 4;
    for (int t = blockIdx.x * 4 + wid; t < tiles; t += gridDim.x * 4) {
        const int row0 = t * 16;
        int arow = row0 + r; if (arow >= N) arow = N - 1;   // clamp (stores guarded)
        bf16x8 afr[4];
        if (!isF32) {
            const unsigned short* xr = (const unsigned short*)x + (size_t)arow * IN_CH;
            #pragma unroll
            for (int ks = 0; ks < 4; ++ks)
                afr[ks] = *(const bf16x8*)&xr[ks * 32 + g * 8];
        } else {
            const float* xr = (const float*)x + (size_t)arow * IN_CH;
            #pragma unroll
            for (int ks = 0; ks < 4; ++ks) {
                f32x4 a0 = *(const f32x4*)&xr[ks * 32 + g * 8];
                f32x4 a1 = *(const f32x4*)&xr[ks * 32 + g * 8 + 4];
                #pragma unroll
                for (int j = 0; j < 4; ++j) {
                    __hip_bfloat16 b0 = __float2bfloat16(a0[j]);
                    __hip_bfloat16 b1v = __float2bfloat16(a1[j]);
                    afr[ks][j]     = *reinterpret_cast<short*>(&b0);
                    afr[ks][j + 4] = *reinterpret_cast<short*>(&b1v);
                }
            }
        }
        f32x4 acc[4] = {};
        #pragma unroll
        for (int ks = 0; ks < 4; ++ks)
            #pragma unroll
            for (int nt = 0; nt < 4; ++nt)
                acc[nt] = __builtin_amdgcn_mfma_f32_16x16x32_bf16(afr[ks], bfr[nt][ks],
                                                                  acc[nt], 0, 0, 0);
        #pragma unroll
        for (int q = 0; q < 4; ++q) {
            int rr = row0 + g * 4 + q;
            if (rr < N) {
                float dv = dinv[rr];
                #pragma unroll
                for (int nt = 0; nt < 4; ++nt)
                    h1s[(size_t)rr * HID + nt * 16 + r] =
                        __float2bfloat16(acc[nt][q] * dv);
            }
        }
    }
}

// ---- Aggregation 1 on pre-scaled features: pure gather-SUM (no per-edge weight).
//      g = relu(d*(h1s[w] + sum_e h1s[r]) + b1); stores gs = g*d (pre-scaled for
//      agg2). Chain per iteration is erow -> gather only (dinv hop eliminated).
__global__ __launch_bounds__(256) void k_agg1(const int* rowstart, const int* erow,
        const __hip_bfloat16* h1s, const float* dinv, const float* b1f,
        __hip_bfloat16* gs, int N) {
    const int lane = threadIdx.x & 63;
    const int sub = lane >> 3;
    const int co  = lane & 7;
    const f32x4 b1a = *(const f32x4*)&b1f[co * 8];
    const f32x4 b1b = *(const f32x4*)&b1f[co * 8 + 4];
    const int wstride = (gridDim.x * 256) >> 6;
    for (int w = (blockIdx.x * 256 + threadIdx.x) >> 6; w < N; w += wstride) {
        int s0 = __builtin_amdgcn_readfirstlane(rowstart[w]);
        int s1 = __builtin_amdgcn_readfirstlane(rowstart[w + 1]);
        float d = dinv[w];
        bf16x8 sv = *(const bf16x8*)&h1s[(size_t)w * HID + co * 8];
        f32x8 acc = {};
        int i = s0 + sub;
        for (; i + 8 < s1; i += 16) {
            int r0 = erow[i], r1 = erow[i + 8];
            f32x8 v0 = cvt8(*(const bf16x8*)&h1s[(size_t)r0 * HID + co * 8]);
            f32x8 v1 = cvt8(*(const bf16x8*)&h1s[(size_t)r1 * HID + co * 8]);
            #pragma unroll
            for (int j = 0; j < 8; ++j) acc[j] += v0[j] + v1[j];
        }
        if (i < s1) {
            int r0 = erow[i];
            f32x8 v0 = cvt8(*(const bf16x8*)&h1s[(size_t)r0 * HID + co * 8]);
            #pragma unroll
            for (int j = 0; j < 8; ++j) acc[j] += v0[j];
        }
        #pragma unroll
        for (int j = 0; j < 8; ++j) {
            acc[j] += __shfl_xor(acc[j], 8);
            acc[j] += __shfl_xor(acc[j], 16);
            acc[j] += __shfl_xor(acc[j], 32);
        }
        if (sub == 0) {
            f32x8 sf = cvt8(sv);
            f32x8 gv;
            #pragma unroll
            for (int j = 0; j < 4; ++j) {
                float ga = fmaxf(fmaf(d, sf[j] + acc[j], b1a[j]), 0.f);
                float gb = fmaxf(fmaf(d, sf[j + 4] + acc[j + 4], b1b[j]), 0.f);
                gv[j]     = ga * d;     // pre-scale for agg2's gather
                gv[j + 4] = gb * d;
            }
            *(bf16x8*)&gs[(size_t)w * HID + co * 8] = pack8(gv);
        }
    }
}

// ---- Aggregation 2 on pre-scaled gs: s[w] = d*(gs[w] + sum_e gs[r]), bf16 out
//      (GEMM2 commutes past aggregation: out = s @ W2 + b2). Same lane map.
__global__ __launch_bounds__(256) void k_agg2s(const int* rowstart, const int* erow,
        const __hip_bfloat16* gs, const float* dinv, __hip_bfloat16* sbuf, int N) {
    const int lane = threadIdx.x & 63;
    const int sub = lane >> 3;
    const int co  = lane & 7;
    const int wstride = (gridDim.x * 256) >> 6;
    for (int w = (blockIdx.x * 256 + threadIdx.x) >> 6; w < N; w += wstride) {
        int s0 = __builtin_amdgcn_readfirstlane(rowstart[w]);
        int s1 = __builtin_amdgcn_readfirstlane(rowstart[w + 1]);
        float d = dinv[w];
        bf16x8 sv = *(const bf16x8*)&gs[(size_t)w * HID + co * 8];
        f32x8 acc = {};
        int i = s0 + sub;
        for (; i + 8 < s1; i += 16) {
            int r0 = erow[i], r1 = erow[i + 8];
            f32x8 v0 = cvt8(*(const bf16x8*)&gs[(size_t)r0 * HID + co * 8]);
            f32x8 v1 = cvt8(*(const bf16x8*)&gs[(size_t)r1 * HID + co * 8]);
            #pragma unroll
            for (int j = 0; j < 8; ++j) acc[j] += v0[j] + v1[j];
        }
        if (i < s1) {
            int r0 = erow[i];
            f32x8 v0 = cvt8(*(const bf16x8*)&gs[(size_t)r0 * HID + co * 8]);
            #pragma unroll
            for (int j = 0; j < 8; ++j) acc[j] += v0[j];
        }
        #pragma unroll
        for (int j = 0; j < 8; ++j) {
            acc[j] += __shfl_xor(acc[j], 8);
            acc[j] += __shfl_xor(acc[j], 16);
            acc[j] += __shfl_xor(acc[j], 32);
        }
        if (sub == 0) {
            f32x8 sf = cvt8(sv);
            f32x8 ov;
            #pragma unroll
            for (int j = 0; j < 8; ++j) ov[j] = d * (sf[j] + acc[j]);
            *(bf16x8*)&sbuf[(size_t)w * HID + co * 8] = pack8(ov);
        }
    }
}

// ---- GEMM2 via MFMA: out[n][c] = sum_k s[n][k]*W2[k][c] + b2[c], f32 out.
__global__ __launch_bounds__(256) void k_gemm2_mfma(const __hip_bfloat16* sbuf,
        const float* W2f, const float* b2f, float* out, int N) {
    __shared__ __align__(16) unsigned short w2T[48][HID];   // W2^T padded, bf16 bits, 6 KB
    for (int i = threadIdx.x; i < 48 * HID; i += 256) {
        int c = i >> 6, k = i & 63;
        float v = (c < OUT_CH) ? W2f[k * OUT_CH + c] : 0.f;
        __hip_bfloat16 b = __float2bfloat16(v);
        w2T[c][k] = *reinterpret_cast<unsigned short*>(&b);
    }
    __syncthreads();

    const int lane = threadIdx.x & 63;
    const int wid  = threadIdx.x >> 6;
    const int r = lane & 15;
    const int gq = lane >> 4;

    bf16x8 bfr[3][2];
    #pragma unroll
    for (int nt = 0; nt < 3; ++nt)
        #pragma unroll
        for (int ks = 0; ks < 2; ++ks)
            bfr[nt][ks] = *(const bf16x8*)&w2T[nt * 16 + r][ks * 32 + gq * 8];
    float b2v[3];
    #pragma unroll
    for (int nt = 0; nt < 3; ++nt)
        b2v[nt] = (nt * 16 + r < OUT_CH) ? b2f[nt * 16 + r] : 0.f;

    const int tiles = (N + 15) >> 4;
    for (int t = blockIdx.x * 4 + wid; t < tiles; t += gridDim.x * 4) {
        const int row0 = t * 16;
        int arow = row0 + r; if (arow >= N) arow = N - 1;
        const unsigned short* sr = (const unsigned short*)sbuf + (size_t)arow * HID;
        bf16x8 afr[2];
        afr[0] = *(const bf16x8*)&sr[gq * 8];
        afr[1] = *(const bf16x8*)&sr[32 + gq * 8];
        f32x4 acc[3] = {};
        #pragma unroll
        for (int ks = 0; ks < 2; ++ks)
            #pragma unroll
            for (int nt = 0; nt < 3; ++nt)
                acc[nt] = __builtin_amdgcn_mfma_f32_16x16x32_bf16(afr[ks], bfr[nt][ks],
                                                                  acc[nt], 0, 0, 0);
        #pragma unroll
        for (int nt = 0; nt < 3; ++nt) {
            int c = nt * 16 + r;
            #pragma unroll
            for (int q = 0; q < 4; ++q) {
                int rr = row0 + gq * 4 + q;
                if (rr < N && c < OUT_CH)
                    out[(size_t)rr * OUT_CH + c] = acc[nt][q] + b2v[nt];
            }
        }
    }
}

extern "C" void kernel_launch(void* const* d_in, const int* in_sizes, int n_in,
                              void* d_out, int out_size, void* d_ws, size_t ws_size,
                              hipStream_t stream) {
    const void* x  = d_in[0];
    const void* ei = d_in[1];
    const void* W1 = d_in[2];
    const void* b1 = d_in[3];
    const void* W2 = d_in[4];
    const void* b2 = d_in[5];
    const int N = in_sizes[0] / IN_CH;   // 100000
    const int E = in_sizes[1] / 2;       // 1600000
    const int* eii = (const int*)ei;

    // ---- workspace layout (4-byte units). bins2 (12.8 MB, 4-byte records)
    //      aliases h1s (bin2->csr complete before gemm1 writes h1s).
    float* ws = (float*)d_ws;
    size_t off = 16;
    int*   flags    = (int*)ws;
    int*   bincnt2  = (int*)ws + off;            off += NBUCK;
    float* dinv     = ws + off;                  off += N;
    float* wf       = ws + off;                  off += 10880;
    int*   rowstart = (int*)ws + off;            off += N + 1;
    off = (off + 255) & ~(size_t)255;
    int*   erow     = (int*)ws + off;            off += E;
    off = (off + 255) & ~(size_t)255;
    __hip_bfloat16* h1s = (__hip_bfloat16*)(ws + off);     off += (size_t)N * HID / 2;
    __hip_bfloat16* gsb = (__hip_bfloat16*)(ws + off);     off += (size_t)N * HID / 2;
    __hip_bfloat16* sbuf = h1s;                  // h1s dead once k_agg1 completes
    unsigned int* bins2 = (unsigned int*)h1s;    // 1024*3125*4B = 12.8MB = h1s

    k_detectconv<<<1, 256, 0, stream>>>(x, ei, flags, W1, b1, W2, b2, wf, bincnt2);

    float invNB = (float)NBUCK / (float)N;
    int nbin = (E + 4095) / 4096;        // 391 blocks x 512 threads
    k_bin2<<<nbin, 512, 0, stream>>>(eii, flags, bincnt2, bins2, E, N, invNB);
    k_csr<<<NBUCK, 256, 0, stream>>>(bins2, bincnt2, rowstart, dinv, erow, N);

    int tiles = (N + 15) / 16;
    int g1 = (tiles + 7) / 8;           // 4 waves/block, 2 tiles/wave
    k_gemm1_mfma<<<g1, 256, 0, stream>>>(x, wf, dinv, h1s, flags, N);

    k_agg1<<<4096, 256, 0, stream>>>(rowstart, erow, h1s, dinv, wf + 8192, gsb, N);
    k_agg2s<<<4096, 256, 0, stream>>>(rowstart, erow, gsb, dinv, sbuf, N);
    k_gemm2_mfma<<<g1, 256, 0, stream>>>(sbuf, wf + 8256, wf + 10816, (float*)d_out, N);
}